// Round 14
// baseline (280.082 us; speedup 1.0000x reference)
//
#include <hip/hip_runtime.h>

typedef int v4i __attribute__((ext_vector_type(4)));

constexpr int Kdim = 4096;
constexpr int Ndim = 4096;
constexpr int MtotC = 8192;
constexpr int BM = 256;
constexpr int BN = 256;
constexpr int NT = 32;            // K-tiles of 128 int8 elems (2 halves of 64)

#define AS1 __attribute__((address_space(1)))
#define AS3 __attribute__((address_space(3)))

// ---------------- pack W int32 -> int8 (16Mi elems, ~83MB traffic) ----------------
__global__ void pack_w_i8(const int* __restrict__ wq, signed char* __restrict__ w8, size_t n4) {
    size_t i = (size_t)blockIdx.x * blockDim.x + threadIdx.x;
    size_t stride = (size_t)gridDim.x * blockDim.x;
    for (size_t j = i; j < n4; j += stride) {
        const int4 v = ((const int4*)wq)[j];
        char4 c;
        c.x = (signed char)v.x; c.y = (signed char)v.y;
        c.z = (signed char)v.z; c.w = (signed char)v.w;
        ((char4*)w8)[j] = c;
    }
}

// ---------------- int8 GEMM, 256x256 tile, fused x int32->int8 A-staging ----------------
// R4-identical schedule/layout/swizzle; A staged from int32 x_q via
// {4x dwordx4 -> v_perm pack -> ds_write_b128}, one 16B granule per phase,
// ping-pong reg sets astA/astB (one granule in flight across each phase boundary).
// W pre-packed to int8 (gload_lds staging, unchanged). Compiler pack-waits form the
// counted-vmcnt drain (B issued before A per phase -> FIFO drains B en route).
__global__ __launch_bounds__(512, 2) void i8gemm_kernel(
    const int* __restrict__ Xq,          // (Mtot, K) int32 (values are int8)
    const signed char* __restrict__ W,   // (N, K) packed int8
    const float* __restrict__ sx,
    const float* __restrict__ wsc,
    const float* __restrict__ bias,
    float* __restrict__ C)
{
    extern __shared__ signed char smem[];

    const int tid  = threadIdx.x;
    const int wave = tid >> 6;
    const int lane = tid & 63;
    const int wr = wave >> 2;     // 0..1  (128-row strip)
    const int wc = wave & 3;      // 0..3  (64-col strip)

    // XCD-aware swizzle: 8 regions of 8bm x 8bn
    const int xr_ = blockIdx.x & 7;
    const int idx = blockIdx.x >> 3;
    const int bm = ((xr_ & 3) * 8 + (idx & 7)) * BM;
    const int bn = ((xr_ >> 2) * 8 + (idx >> 3)) * BN;

    // ---- staging constants ----
    const int srow_in = wave * 16 + (lane >> 2);            // 0..127
    const int sslotp  = lane & 3;                           // LDS 16B slot'
    const int gslot   = sslotp ^ ((srow_in >> 1) & 3);      // pre-inverse-swizzled source slot
    const int* Xg = Xq + (size_t)(bm + srow_in) * Kdim + gslot * 16;          // int32 units
    const signed char* Wg = W + (size_t)(bn + srow_in) * Kdim + gslot * 16;   // bytes
    const int sdst = srow_in * 64 + sslotp * 16;            // within-region LDS offset

    // ---- fragment read constants (16x16x64: row/col = lane&15, 16B k-slot = lane>>4) ----
    const int frow = lane & 15;
    const int fsl  = lane >> 4;
    const int rsw  = ((fsl ^ ((frow >> 1) & 3)) << 4);      // swizzled 16B slot byte
    const int aro  = (wr * 128 + frow) * 64 + rsw;          // + f*1024 + half*32768
    const int bro  = 16384 + (wc * 64 + frow) * 64 + rsw;   // + g*1024 + half*32768

    v4i acc[8][4];
#pragma unroll
    for (int f = 0; f < 8; ++f)
#pragma unroll
        for (int g = 0; g < 4; ++g)
#pragma unroll
            for (int e = 0; e < 4; ++e) acc[f][g][e] = 0;

    v4i astA[4], astB[4];   // in-flight int32 A-granules (ping-pong, static names)

// issue 4 dwordx4 int32 loads for one staged 16B granule (KT,HALF, row-block R)
#define AISS(SET, KT, HALF, R) do {                                                    \
    _Pragma("unroll") for (int j_ = 0; j_ < 4; ++j_)                                   \
        SET[j_] = *(const v4i*)(Xg + (size_t)((R) * 128) * Kdim                        \
                                + (size_t)(KT) * 128 + (HALF) * 64 + j_ * 4);          \
} while (0)

// pack 16 int32 (low bytes) -> 16B int8, ds_write_b128 into the R4-identical layout
#define PACKST(SET, KT, HALF, R) do {                                                  \
    v4i wv_;                                                                           \
    _Pragma("unroll") for (int d_ = 0; d_ < 4; ++d_) {                                 \
        unsigned p1_ = __builtin_amdgcn_perm((unsigned)SET[d_][1], (unsigned)SET[d_][0], 0x00000400u); \
        unsigned p2_ = __builtin_amdgcn_perm((unsigned)SET[d_][3], (unsigned)SET[d_][2], 0x00000400u); \
        wv_[d_] = (int)__builtin_amdgcn_perm(p2_, p1_, 0x05040100u);                   \
    }                                                                                  \
    *(v4i*)(smem + (size_t)(((KT) & 1) * 65536 + (HALF) * 32768 + (R) * 8192 + sdst)) = wv_; \
} while (0)

// B staging: 2 global_load_lds (row-blocks 0,128) — unchanged from R4
#define BISS(KT, HALF) do {                                                            \
    const signed char* sb_ = Wg + (size_t)(KT) * 128 + (HALF) * 64;                    \
    signed char* db_ = smem + ((KT) & 1) * 65536 + (HALF) * 32768 + 16384 + sdst;      \
    __builtin_amdgcn_global_load_lds((const AS1 void*)sb_,                        (AS3 void*)db_,          16, 0, 0); \
    __builtin_amdgcn_global_load_lds((const AS1 void*)(sb_ + (size_t)128 * Kdim), (AS3 void*)(db_ + 8192), 16, 0, 0); \
} while (0)

#define BAR   __builtin_amdgcn_s_barrier()
#define LGKM0 asm volatile("s_waitcnt lgkmcnt(0)" ::: "memory")
#define PRIO1 __builtin_amdgcn_s_setprio(1)
#define PRIO0 __builtin_amdgcn_s_setprio(0)

#define PH_READ_AB(HALF) do {                                                          \
    _Pragma("unroll") for (int g_ = 0; g_ < 4; ++g_)                                   \
        bv[g_] = *(const v4i*)(bufb + (HALF) * 32768 + bro + g_ * 1024);               \
    _Pragma("unroll") for (int f_ = 0; f_ < 4; ++f_)                                   \
        av[f_] = *(const v4i*)(bufb + (HALF) * 32768 + aro + f_ * 1024);               \
} while (0)

#define PH_READ_A4(HALF) do {                                                          \
    _Pragma("unroll") for (int f_ = 0; f_ < 4; ++f_)                                   \
        av[f_] = *(const v4i*)(bufb + (HALF) * 32768 + aro + (4 + f_) * 1024);         \
} while (0)

#define MFMA_BLOCK(FB) do {                                                            \
    _Pragma("unroll") for (int f_ = 0; f_ < 4; ++f_)                                   \
    _Pragma("unroll") for (int g_ = 0; g_ < 4; ++g_)                                   \
        acc[(FB) + f_][g_] = __builtin_amdgcn_mfma_i32_16x16x64_i8(                    \
            av[f_], bv[g_], acc[(FB) + f_][g_], 0, 0, 0);                              \
} while (0)

    // ---- prologue: halves 0H0, 0H1, 1H0 fully staged; 1H0r1 left in-flight in astB ----
    BISS(0, 0);
    AISS(astA, 0, 0, 0); PACKST(astA, 0, 0, 0);
    AISS(astA, 0, 0, 1); PACKST(astA, 0, 0, 1);
    BISS(0, 1);
    AISS(astA, 0, 1, 0); PACKST(astA, 0, 1, 0);
    AISS(astA, 0, 1, 1); PACKST(astA, 0, 1, 1);
    BISS(1, 0);
    AISS(astA, 1, 0, 0); PACKST(astA, 1, 0, 0);
    AISS(astB, 1, 0, 1);                       // packed at ph1 of u=0
    LGKM0;
    BAR;

    for (int u = 0; u < NT; ++u) {
        const signed char* bufb = smem + (u & 1) * 65536;
        v4i av[4], bv[4];
        // ---- ph1: frags H0 f0-3; B(u+1).H1; issue A(u+1).H1r0; pack (u+1).H0r1 ----
        PH_READ_AB(0);
        if (u < NT - 1) {
            BISS(u + 1, 1);
            AISS(astA, u + 1, 1, 0);
            PACKST(astB, u + 1, 0, 1);
        }
        BAR; LGKM0; PRIO1; MFMA_BLOCK(0); PRIO0; BAR;
        // ---- ph2: frags H0 f4-7; issue A(u+1).H1r1; pack (u+1).H1r0 ----
        PH_READ_A4(0);
        if (u < NT - 1) {
            AISS(astB, u + 1, 1, 1);
            PACKST(astA, u + 1, 1, 0);
        }
        BAR; LGKM0; PRIO1; MFMA_BLOCK(4); PRIO0; BAR;
        // ---- ph3: frags H1 f0-3; B(u+2).H0; issue A(u+2).H0r0; pack (u+1).H1r1 ----
        PH_READ_AB(1);
        if (u < NT - 2) {
            BISS(u + 2, 0);
            AISS(astA, u + 2, 0, 0);
        }
        if (u < NT - 1) PACKST(astB, u + 1, 1, 1);
        BAR; LGKM0; PRIO1; MFMA_BLOCK(0); PRIO0; BAR;
        // ---- ph4: frags H1 f4-7; issue A(u+2).H0r1; pack (u+2).H0r0 ----
        PH_READ_A4(1);
        if (u < NT - 2) {
            AISS(astB, u + 2, 0, 1);
            PACKST(astA, u + 2, 0, 0);
        }
        BAR; LGKM0; PRIO1; MFMA_BLOCK(4); PRIO0; BAR;
    }

    // ---- epilogue: dequant + bias, fp32 store ----
    // 16x16 C/D map: col = lane&15, row = (lane>>4)*4 + reg
    const int orow0 = bm + wr * 128;
    const int ocol0 = bn + wc * 64;
    float wsv[4], bvv[4];
#pragma unroll
    for (int g = 0; g < 4; ++g) {
        const int col = ocol0 + g * 16 + frow;
        wsv[g] = wsc[col];
        bvv[g] = bias[col];
    }
#pragma unroll
    for (int f = 0; f < 8; ++f) {
#pragma unroll
        for (int jr = 0; jr < 4; ++jr) {
            const int row = orow0 + f * 16 + fsl * 4 + jr;
            const float s = sx[row];
#pragma unroll
            for (int g = 0; g < 4; ++g) {
                const int col = ocol0 + g * 16 + frow;
                C[(size_t)row * Ndim + col] = (float)acc[f][g][jr] * s * wsv[g] + bvv[g];
            }
        }
    }
#undef AISS
#undef PACKST
#undef BISS
#undef BAR
#undef LGKM0
#undef PRIO1
#undef PRIO0
#undef PH_READ_AB
#undef PH_READ_A4
#undef MFMA_BLOCK
}

extern "C" void kernel_launch(void* const* d_in, const int* in_sizes, int n_in,
                              void* d_out, int out_size, void* d_ws, size_t ws_size,
                              hipStream_t stream) {
    (void)in_sizes; (void)n_in; (void)out_size; (void)ws_size;
    const int*   x_q  = (const int*)d_in[0];
    const float* sx   = (const float*)d_in[1];
    const int*   w_q  = (const int*)d_in[2];
    const float* wsc  = (const float*)d_in[3];
    const float* bias = (const float*)d_in[4];
    float* out = (float*)d_out;

    signed char* w8 = (signed char*)d_ws;
    const size_t nw = (size_t)Ndim * Kdim;    // 16 Mi

    pack_w_i8<<<1024, 256, 0, stream>>>(w_q, w8, nw / 4);

    static bool attr_set = false;
    if (!attr_set) {
        hipFuncSetAttribute((const void*)i8gemm_kernel,
                            hipFuncAttributeMaxDynamicSharedMemorySize, 131072);
        attr_set = true;
    }

    const int nwg = (MtotC / BM) * (Ndim / BN);  // 512
    i8gemm_kernel<<<nwg, 512, 131072, stream>>>(x_q, w8, sx, wsc, bias, out);
}

// Round 15
// 198.446 us; speedup vs baseline: 1.4114x; 1.4114x over previous
//
#include <hip/hip_runtime.h>

typedef int v4i __attribute__((ext_vector_type(4)));

constexpr int Kdim = 4096;
constexpr int Ndim = 4096;
constexpr int MtotC = 8192;
constexpr int BM = 256;
constexpr int BN = 256;
constexpr int BKB = 128;          // K-bytes per K-tile (2 halves of 64B)
constexpr int NT = Kdim / BKB;    // 32 K-tiles

#define AS1 __attribute__((address_space(1)))
#define AS3 __attribute__((address_space(3)))

// ---------------- pack int32 -> int8 (both tensors, one launch) ----------------
__global__ void pack_i32_to_i8(const int* __restrict__ xq, const int* __restrict__ wq,
                               signed char* __restrict__ x8, signed char* __restrict__ w8,
                               size_t nx4, size_t nw4) {
    size_t i = (size_t)blockIdx.x * blockDim.x + threadIdx.x;
    size_t stride = (size_t)gridDim.x * blockDim.x;
    size_t tot = nx4 + nw4;
    for (size_t j = i; j < tot; j += stride) {
        if (j < nx4) {
            const int4 v = ((const int4*)xq)[j];
            char4 c;
            c.x = (signed char)v.x; c.y = (signed char)v.y;
            c.z = (signed char)v.z; c.w = (signed char)v.w;
            ((char4*)x8)[j] = c;
        } else {
            const size_t k = j - nx4;
            const int4 v = ((const int4*)wq)[k];
            char4 c;
            c.x = (signed char)v.x; c.y = (signed char)v.y;
            c.z = (signed char)v.z; c.w = (signed char)v.w;
            ((char4*)w8)[k] = c;
        }
    }
}

// ---------------- int8 GEMM, 256x256 tile, 4 waves of 128x128, acc in AGPR ----------------
// Wave tile 128x128: 128 int8-ops per LDS byte -> LDS port (~1714 cyc/K-tile/CU)
// well below MFMA floor (~2613) -> MFMA-bound geometry. Accumulator (64 x v4i)
// forced into AGPRs via inline-asm "a" constraints; operand reg-double-buffer
// (R13 schedule, doubled ledger). 1 wave/SIMD.
// LDS: 2 bufs x 2 halves x (A 16KB + B 16KB) = 128KB.
// 16B-slot swizzle within a 64B row: slot' = slot ^ ((row>>1)&3)  (verified 0-conflict).
__global__ __launch_bounds__(256, 1) void i8gemm_kernel(
    const signed char* __restrict__ A,
    const signed char* __restrict__ W,
    const float* __restrict__ sx,
    const float* __restrict__ wsc,
    const float* __restrict__ bias,
    float* __restrict__ C)
{
    extern __shared__ signed char smem[];

    const int tid  = threadIdx.x;
    const int wave = tid >> 6;
    const int lane = tid & 63;
    const int wr = wave >> 1;     // 0..1  (128-row strip)
    const int wc = wave & 1;      // 0..1  (128-col strip)

    // XCD-aware swizzle: 8 regions of 8bm x 8bn
    const int xr_ = blockIdx.x & 7;
    const int idx = blockIdx.x >> 3;
    const int bm = ((xr_ & 3) * 8 + (idx & 7)) * BM;
    const int bn = ((xr_ >> 2) * 8 + (idx >> 3)) * BN;

    // ---- staging constants (8 gload_lds per thread per half-stage) ----
    const int srow  = tid >> 2;                             // 0..63
    const int gslot = (tid & 3) ^ ((srow >> 1) & 3);        // pre-inverse-swizzled 16B slot
    const signed char* Ag = A + (size_t)(bm + srow) * Kdim + gslot * 16;
    const signed char* Wg = W + (size_t)(bn + srow) * Kdim + gslot * 16;

    // ---- fragment read constants (16x16x64: row/col = lane&15, 16B k-slot = lane>>4) ----
    const int frow = lane & 15;
    const int fsl  = lane >> 4;
    const int rsw  = ((fsl ^ ((frow >> 1) & 3)) << 4);      // swizzled 16B slot byte
    const int aro  = (wr * 128 + frow) * 64 + rsw;          // + f*1024 + half*32768
    const int bro  = 16384 + (wc * 128 + frow) * 64 + rsw;  // + g*1024 + half*32768

    // accumulator in AGPRs (64 x v4i = 256 AGPR)
    v4i acc[8][8];
#pragma unroll
    for (int f = 0; f < 8; ++f)
#pragma unroll
        for (int g = 0; g < 8; ++g)
#pragma unroll
            for (int e = 0; e < 4; ++e) acc[f][g][e] = 0;

    v4i avA[8], bvA[8], avB[8], bvB[8];   // static ping-pong operand sets (rule #20)

#define STG_HALF(KT, HALF) do {                                                        \
    signed char* dst = smem + ((KT) & 1) * 65536 + (HALF) * 32768 + tid * 16;          \
    const signed char* sa = Ag + (size_t)(KT) * BKB + (HALF) * 64;                     \
    const signed char* sb = Wg + (size_t)(KT) * BKB + (HALF) * 64;                     \
    _Pragma("unroll") for (int r_ = 0; r_ < 4; ++r_)                                   \
        __builtin_amdgcn_global_load_lds((const AS1 void*)(sa + (size_t)(r_ * 64) * Kdim), \
                                         (AS3 void*)(dst + r_ * 4096), 16, 0, 0);      \
    _Pragma("unroll") for (int r_ = 0; r_ < 4; ++r_)                                   \
        __builtin_amdgcn_global_load_lds((const AS1 void*)(sb + (size_t)(r_ * 64) * Kdim), \
                                         (AS3 void*)(dst + 16384 + r_ * 4096), 16, 0, 0); \
} while (0)

#define READ_SET(AV, BV, BASE, HALF) do {                                              \
    _Pragma("unroll") for (int g_ = 0; g_ < 8; ++g_)                                   \
        BV[g_] = *(const v4i*)((BASE) + (HALF) * 32768 + bro + g_ * 1024);             \
    _Pragma("unroll") for (int f_ = 0; f_ < 8; ++f_)                                   \
        AV[f_] = *(const v4i*)((BASE) + (HALF) * 32768 + aro + f_ * 1024);             \
} while (0)

// MFMA with acc pinned to AGPRs ("a" constraint, input tied to output)
#define MFMA_SET(AV, BV) do {                                                          \
    _Pragma("unroll") for (int f_ = 0; f_ < 8; ++f_)                                   \
    _Pragma("unroll") for (int g_ = 0; g_ < 8; ++g_)                                   \
        asm("v_mfma_i32_16x16x64_i8 %0, %1, %2, %0"                                    \
            : "+a"(acc[f_][g_]) : "v"(AV[f_]), "v"(BV[g_]));                           \
} while (0)

#define BAR   __builtin_amdgcn_s_barrier()
#define LGKM0 asm volatile("s_waitcnt lgkmcnt(0)" ::: "memory")

    // ---- prologue: stage halves 0H0,0H1,1H0,1H1 (32 loads, FIFO); read 0H0 -> setA ----
    STG_HALF(0, 0);
    STG_HALF(0, 1);
    STG_HALF(1, 0);
    STG_HALF(1, 1);
    asm volatile("s_waitcnt vmcnt(24)" ::: "memory");   // drain 0H0
    BAR;
    READ_SET(avA, bvA, smem, 0);

    // ---- steady loop: u = 0..29 ----
    for (int u = 0; u < NT - 2; ++u) {
        signed char* bufc = smem + (u & 1) * 65536;
        signed char* bufn = smem + ((u + 1) & 1) * 65536;
        // phase 2u: MFMA half 2u (setA); read half 2u+1 -> setB; stage (u+2).H0
        asm volatile("s_waitcnt vmcnt(16)" ::: "memory");   // u.H1 landed
        BAR;
        STG_HALF(u + 2, 0);
        READ_SET(avB, bvB, bufc, 1);
        MFMA_SET(avA, bvA);
        LGKM0;
        // phase 2u+1: MFMA half 2u+1 (setB); read half 2u+2 -> setA; stage (u+2).H1
        asm volatile("s_waitcnt vmcnt(16)" ::: "memory");   // (u+1).H0 landed
        BAR;
        STG_HALF(u + 2, 1);
        READ_SET(avA, bvA, bufn, 0);
        MFMA_SET(avB, bvB);
        LGKM0;
    }

    // ---- u = 30: no more staging ----
    {
        signed char* bufc = smem;            // buf[0]
        signed char* bufn = smem + 65536;    // buf[1]
        asm volatile("s_waitcnt vmcnt(16)" ::: "memory");   // 30.H1 landed
        BAR;
        READ_SET(avB, bvB, bufc, 1);
        MFMA_SET(avA, bvA);
        LGKM0;
        asm volatile("s_waitcnt vmcnt(8)" ::: "memory");    // 31.H0 landed
        BAR;
        READ_SET(avA, bvA, bufn, 0);
        MFMA_SET(avB, bvB);
        LGKM0;
    }
    // ---- u = 31 ----
    {
        signed char* bufc = smem + 65536;    // buf[1]
        asm volatile("s_waitcnt vmcnt(0)" ::: "memory");    // 31.H1 landed
        BAR;
        READ_SET(avB, bvB, bufc, 1);
        MFMA_SET(avA, bvA);
        LGKM0;
        MFMA_SET(avB, bvB);                  // final half
    }

    // ---- epilogue: dequant + bias, fp32 store ----
    // 16x16 C/D map: col = lane&15, row = (lane>>4)*4 + reg
    const int orow0 = bm + wr * 128;
    const int ocol0 = bn + wc * 128;
    float wsv[8], bvv[8];
#pragma unroll
    for (int g = 0; g < 8; ++g) {
        const int col = ocol0 + g * 16 + frow;
        wsv[g] = wsc[col];
        bvv[g] = bias[col];
    }
#pragma unroll
    for (int f = 0; f < 8; ++f) {
#pragma unroll
        for (int jr = 0; jr < 4; ++jr) {
            const int row = orow0 + f * 16 + fsl * 4 + jr;
            const float s = sx[row];
#pragma unroll
            for (int g = 0; g < 8; ++g) {
                const int col = ocol0 + g * 16 + frow;
                C[(size_t)row * Ndim + col] = (float)acc[f][g][jr] * s * wsv[g] + bvv[g];
            }
        }
    }
#undef STG_HALF
#undef READ_SET
#undef MFMA_SET
#undef BAR
#undef LGKM0
}

extern "C" void kernel_launch(void* const* d_in, const int* in_sizes, int n_in,
                              void* d_out, int out_size, void* d_ws, size_t ws_size,
                              hipStream_t stream) {
    (void)in_sizes; (void)n_in; (void)out_size; (void)ws_size;
    const int*   x_q  = (const int*)d_in[0];
    const float* sx   = (const float*)d_in[1];
    const int*   w_q  = (const int*)d_in[2];
    const float* wsc  = (const float*)d_in[3];
    const float* bias = (const float*)d_in[4];
    float* out = (float*)d_out;

    signed char* x8 = (signed char*)d_ws;
    signed char* w8 = x8 + (size_t)MtotC * Kdim;

    const size_t nx = (size_t)MtotC * Kdim;   // 32 Mi
    const size_t nw = (size_t)Ndim * Kdim;    // 16 Mi

    pack_i32_to_i8<<<3072, 256, 0, stream>>>(x_q, w_q, x8, w8, nx / 4, nw / 4);

    static bool attr_set = false;
    if (!attr_set) {
        hipFuncSetAttribute((const void*)i8gemm_kernel,
                            hipFuncAttributeMaxDynamicSharedMemorySize, 131072);
        attr_set = true;
    }

    const int nwg = (MtotC / BM) * (Ndim / BN);  // 512
    i8gemm_kernel<<<nwg, 256, 131072, stream>>>(x8, w8, sx, wsc, bias, out);
}

// Round 18
// 188.108 us; speedup vs baseline: 1.4889x; 1.0550x over previous
//
#include <hip/hip_runtime.h>

typedef int v4i __attribute__((ext_vector_type(4)));

constexpr int Kdim = 4096;
constexpr int Ndim = 4096;
constexpr int MtotC = 8192;
constexpr int BM = 256;
constexpr int BN = 256;
constexpr int NH = 64;            // 64 K-halves of 64B

#define AS1 __attribute__((address_space(1)))
#define AS3 __attribute__((address_space(3)))

// ---------------- pack int32 -> int8 (both tensors, one launch) ----------------
__global__ void pack_i32_to_i8(const int* __restrict__ xq, const int* __restrict__ wq,
                               signed char* __restrict__ x8, signed char* __restrict__ w8,
                               size_t nx4, size_t nw4) {
    size_t i = (size_t)blockIdx.x * blockDim.x + threadIdx.x;
    size_t stride = (size_t)gridDim.x * blockDim.x;
    size_t tot = nx4 + nw4;
    for (size_t j = i; j < tot; j += stride) {
        if (j < nx4) {
            const int4 v = ((const int4*)xq)[j];
            char4 c;
            c.x = (signed char)v.x; c.y = (signed char)v.y;
            c.z = (signed char)v.z; c.w = (signed char)v.w;
            ((char4*)x8)[j] = c;
        } else {
            const size_t k = j - nx4;
            const int4 v = ((const int4*)wq)[k];
            char4 c;
            c.x = (signed char)v.x; c.y = (signed char)v.y;
            c.z = (signed char)v.z; c.w = (signed char)v.w;
            ((char4*)w8)[k] = c;
        }
    }
}

// ---------------- int8 GEMM, 256x256, counted-lgkm register-dbuf pipeline ----------------
// Phase q (one 64B K-half): vmcnt(4); BAR; stage half q+3 (4 gload_lds);
// issue 12 ds_reads of half q+1 -> spare regset; s_waitcnt lgkmcnt(12) (drains ONLY
// the previous set); MFMA half q on current regset. No full lgkm drain before
// barrier-arrival (R13's residual serialization removed).
// LDS: 4 half-regions of 32KB (A 16KB + B 16KB): region(m) = (m>>1)&1 buf, (m&1) half.
// 16B-slot swizzle within a 64B row: slot' = slot ^ ((row>>1)&3)  (verified 0-conflict).
__global__ __launch_bounds__(512, 2) void i8gemm_kernel(
    const signed char* __restrict__ A,
    const signed char* __restrict__ W,
    const float* __restrict__ sx,
    const float* __restrict__ wsc,
    const float* __restrict__ bias,
    float* __restrict__ C)
{
    extern __shared__ signed char smem[];

    const int tid  = threadIdx.x;
    const int wave = tid >> 6;
    const int lane = tid & 63;
    const int wr = wave >> 2;     // 0..1  (128-row strip)
    const int wc = wave & 3;      // 0..3  (64-col strip)

    // XCD-aware swizzle: 8 regions of 8bm x 8bn
    const int xr_ = blockIdx.x & 7;
    const int idx = blockIdx.x >> 3;
    const int bm = ((xr_ & 3) * 8 + (idx & 7)) * BM;
    const int bn = ((xr_ >> 2) * 8 + (idx >> 3)) * BN;

    // ---- staging constants (4 gload_lds per thread per half) ----
    const int srow  = tid >> 2;                             // 0..127
    const int gslot = (tid & 3) ^ ((srow >> 1) & 3);        // pre-inverse-swizzled 16B slot
    const signed char* Ag = A + (size_t)(bm + srow) * Kdim + gslot * 16;
    const signed char* Wg = W + (size_t)(bn + srow) * Kdim + gslot * 16;
    const int sdst = srow * 64 + (tid & 3) * 16;            // linear lane-contiguous dest

    // ---- fragment read constants (16x16x64: row/col = lane&15, 16B k-slot = lane>>4) ----
    const int frow = lane & 15;
    const int fsl  = lane >> 4;
    const int rsw  = ((fsl ^ ((frow >> 1) & 3)) << 4);      // swizzled 16B slot byte
    const int aro  = (wr * 128 + frow) * 64 + rsw;          // + f*1024 (+ region base)
    const int bro  = 16384 + (wc * 64 + frow) * 64 + rsw;   // + g*1024 (+ region base)

    v4i acc[8][4];
#pragma unroll
    for (int f = 0; f < 8; ++f)
#pragma unroll
        for (int g = 0; g < 4; ++g)
#pragma unroll
            for (int e = 0; e < 4; ++e) acc[f][g][e] = 0;

    v4i avA[8], bvA[4], avB[8], bvB[4];   // static ping-pong (rule #20)

// region base of K-half M
#define REG_OF(M) ((((M) >> 1) & 1) * 65536 + ((M) & 1) * 32768)

#define STG_HALF(M) do {                                                               \
    signed char* dst = smem + REG_OF(M) + sdst;                                        \
    const signed char* sa = Ag + (size_t)(M) * 64;                                     \
    const signed char* sb = Wg + (size_t)(M) * 64;                                     \
    __builtin_amdgcn_global_load_lds((const AS1 void*)sa,                        (AS3 void*)dst,           16, 0, 0); \
    __builtin_amdgcn_global_load_lds((const AS1 void*)(sa + (size_t)128 * Kdim), (AS3 void*)(dst + 8192),  16, 0, 0); \
    __builtin_amdgcn_global_load_lds((const AS1 void*)sb,                        (AS3 void*)(dst + 16384), 16, 0, 0); \
    __builtin_amdgcn_global_load_lds((const AS1 void*)(sb + (size_t)128 * Kdim), (AS3 void*)(dst + 24576), 16, 0, 0); \
} while (0)

#define READ_SET(AV, BV, M) do {                                                       \
    const signed char* base_ = smem + REG_OF(M);                                       \
    _Pragma("unroll") for (int g_ = 0; g_ < 4; ++g_)                                   \
        BV[g_] = *(const v4i*)(base_ + bro + g_ * 1024);                               \
    _Pragma("unroll") for (int f_ = 0; f_ < 8; ++f_)                                   \
        AV[f_] = *(const v4i*)(base_ + aro + f_ * 1024);                               \
} while (0)

#define MFMA_SET(AV, BV) do {                                                          \
    __builtin_amdgcn_s_setprio(1);                                                     \
    _Pragma("unroll") for (int f_ = 0; f_ < 8; ++f_)                                   \
    _Pragma("unroll") for (int g_ = 0; g_ < 4; ++g_)                                   \
        acc[f_][g_] = __builtin_amdgcn_mfma_i32_16x16x64_i8(AV[f_], BV[g_], acc[f_][g_], 0, 0, 0); \
    __builtin_amdgcn_s_setprio(0);                                                     \
} while (0)

#define BAR     __builtin_amdgcn_s_barrier()
#define LGKM12  do { asm volatile("s_waitcnt lgkmcnt(12)" ::: "memory");               \
                     __builtin_amdgcn_sched_barrier(0); } while (0)
#define LGKM0   do { asm volatile("s_waitcnt lgkmcnt(0)" ::: "memory");                \
                     __builtin_amdgcn_sched_barrier(0); } while (0)
#define VMC(N)  asm volatile("s_waitcnt vmcnt(" #N ")" ::: "memory")

    // ---- prologue: stage halves 0,1,2 (12 loads); drain half 0; read half 0 -> setA ----
    STG_HALF(0);
    STG_HALF(1);
    STG_HALF(2);
    VMC(8);                 // drain half 0 (leaves 1,2)
    BAR;
    READ_SET(avA, bvA, 0);

    // ---- steady: u = 0..29 (phases 2u, 2u+1) ----
    for (int u = 0; u < 30; ++u) {
        const int q = 2 * u;
        // phase q (even): MFMA setA(half q); read half q+1 -> setB; stage half q+3
        VMC(4);             // drain half q+1 (leaves q+2)
        BAR;
        STG_HALF(q + 3);
        READ_SET(avB, bvB, q + 1);
        LGKM12;             // drain setA's reads only
        MFMA_SET(avA, bvA);
        // phase q+1 (odd): MFMA setB(half q+1); read half q+2 -> setA; stage half q+4
        VMC(4);             // drain half q+2 (leaves q+3)
        BAR;
        STG_HALF(q + 4);
        READ_SET(avA, bvA, q + 2);
        LGKM12;             // drain setB's reads only
        MFMA_SET(avB, bvB);
    }

    // ---- u = 30 (phases 60, 61) ----
    VMC(4);                 // drain half 61 (leaves 62)
    BAR;
    STG_HALF(63);
    READ_SET(avB, bvB, 61);
    LGKM12;
    MFMA_SET(avA, bvA);
    VMC(4);                 // drain half 62 (leaves 63)
    BAR;
    READ_SET(avA, bvA, 62);
    LGKM12;
    MFMA_SET(avB, bvB);

    // ---- u = 31 (phases 62, 63) ----
    VMC(0);                 // drain half 63
    BAR;
    READ_SET(avB, bvB, 63);
    LGKM12;
    MFMA_SET(avA, bvA);
    LGKM0;
    MFMA_SET(avB, bvB);

    // ---- epilogue: dequant + bias, fp32 store ----
    // 16x16 C/D map: col = lane&15, row = (lane>>4)*4 + reg
    const int orow0 = bm + wr * 128;
    const int ocol0 = bn + wc * 64;
    float wsv[4], bvv[4];
#pragma unroll
    for (int g = 0; g < 4; ++g) {
        const int col = ocol0 + g * 16 + frow;
        wsv[g] = wsc[col];
        bvv[g] = bias[col];
    }
#pragma unroll
    for (int f = 0; f < 8; ++f) {
#pragma unroll
        for (int jr = 0; jr < 4; ++jr) {
            const int row = orow0 + f * 16 + fsl * 4 + jr;
            const float s = sx[row];
#pragma unroll
            for (int g = 0; g < 4; ++g) {
                const int col = ocol0 + g * 16 + frow;
                C[(size_t)row * Ndim + col] = (float)acc[f][g][jr] * s * wsv[g] + bvv[g];
            }
        }
    }
#undef REG_OF
#undef STG_HALF
#undef READ_SET
#undef MFMA_SET
#undef BAR
#undef LGKM12
#undef LGKM0
#undef VMC
}

extern "C" void kernel_launch(void* const* d_in, const int* in_sizes, int n_in,
                              void* d_out, int out_size, void* d_ws, size_t ws_size,
                              hipStream_t stream) {
    (void)in_sizes; (void)n_in; (void)out_size; (void)ws_size;
    const int*   x_q  = (const int*)d_in[0];
    const float* sx   = (const float*)d_in[1];
    const int*   w_q  = (const int*)d_in[2];
    const float* wsc  = (const float*)d_in[3];
    const float* bias = (const float*)d_in[4];
    float* out = (float*)d_out;

    signed char* x8 = (signed char*)d_ws;
    signed char* w8 = x8 + (size_t)MtotC * Kdim;

    const size_t nx = (size_t)MtotC * Kdim;   // 32 Mi
    const size_t nw = (size_t)Ndim * Kdim;    // 16 Mi

    pack_i32_to_i8<<<3072, 256, 0, stream>>>(x_q, w_q, x8, w8, nx / 4, nw / 4);

    static bool attr_set = false;
    if (!attr_set) {
        hipFuncSetAttribute((const void*)i8gemm_kernel,
                            hipFuncAttributeMaxDynamicSharedMemorySize, 131072);
        attr_set = true;
    }

    const int nwg = (MtotC / BM) * (Ndim / BN);  // 512
    i8gemm_kernel<<<nwg, 512, 131072, stream>>>(x8, w8, sx, wsc, bias, out);
}